// Round 1
// baseline (5174.014 us; speedup 1.0000x reference)
//
#include <hip/hip_runtime.h>
#include <cmath>

#define T_SEQ 2048
#define C_DIM 1024

// ---------------------------------------------------------------------------
// Generic tiled f32 GEMM:  C[M,N] = A[M,K] @ W^T, where W is [N,K] row-major.
// EPI 0: C = acc.   EPI 1: C = C * acc  (fused final elementwise multiply).
// Tiles: BM=BN=64, BK=32; 256 threads; 4x4 outputs/thread.
// All dims assumed multiples of 64/32 (true for this problem).
// ---------------------------------------------------------------------------
template<int EPI>
__global__ __launch_bounds__(256)
void gemm_bt(const float* __restrict__ A, const float* __restrict__ W,
             float* __restrict__ C, int M, int N, int K)
{
    __shared__ float As[32][68];   // [k][m], pad to 68 (272B row, 16B aligned)
    __shared__ float Bs[32][68];   // [k][n]
    const int tid = threadIdx.x;
    const int m0 = blockIdx.y * 64;
    const int n0 = blockIdx.x * 64;
    const int tm = tid >> 4;          // 0..15
    const int tn = tid & 15;          // 0..15
    const int lr = tid >> 3;          // 0..31
    const int lk = (tid & 7) << 2;    // 0,4,...,28

    float acc[4][4] = {};

    for (int k0 = 0; k0 < K; k0 += 32) {
        // A tile: As[kk][mm] = A[m0+mm][k0+kk]  (float4 along K)
        #pragma unroll
        for (int p = 0; p < 2; ++p) {
            const int mm = lr + p * 32;
            const float4 v = *reinterpret_cast<const float4*>(
                &A[(size_t)(m0 + mm) * K + k0 + lk]);
            As[lk + 0][mm] = v.x; As[lk + 1][mm] = v.y;
            As[lk + 2][mm] = v.z; As[lk + 3][mm] = v.w;
        }
        // B tile: Bs[kk][nn] = W[(n0+nn)*K + k0+kk]  (W^T access, float4 along K)
        #pragma unroll
        for (int p = 0; p < 2; ++p) {
            const int nn = lr + p * 32;
            const float4 v = *reinterpret_cast<const float4*>(
                &W[(size_t)(n0 + nn) * K + k0 + lk]);
            Bs[lk + 0][nn] = v.x; Bs[lk + 1][nn] = v.y;
            Bs[lk + 2][nn] = v.z; Bs[lk + 3][nn] = v.w;
        }
        __syncthreads();
        #pragma unroll
        for (int kk = 0; kk < 32; ++kk) {
            float a[4], b[4];
            #pragma unroll
            for (int i = 0; i < 4; ++i) a[i] = As[kk][tm * 4 + i];
            #pragma unroll
            for (int j = 0; j < 4; ++j) b[j] = Bs[kk][tn * 4 + j];
            #pragma unroll
            for (int i = 0; i < 4; ++i)
                #pragma unroll
                for (int j = 0; j < 4; ++j)
                    acc[i][j] = fmaf(a[i], b[j], acc[i][j]);
        }
        __syncthreads();
    }

    #pragma unroll
    for (int i = 0; i < 4; ++i) {
        const size_t row = (size_t)(m0 + tm * 4 + i);
        #pragma unroll
        for (int j = 0; j < 4; ++j) {
            const size_t idx = row * N + (n0 + tn * 4 + j);
            if (EPI == 0) C[idx] = acc[i][j];
            else          C[idx] = C[idx] * acc[i][j];
        }
    }
}

// ---------------------------------------------------------------------------
// Causal 2-tap conv as GEMM: C[M,N] = shiftT(A) @ W[0] + A @ W[1]
//   W is [2,K,N] row-major (WIO layout, direct).
//   shiftT: output row (b,t) reads A row (b,t-1); zeros at t==0 (per batch).
// GATE 0: C = acc.
// GATE 1: Fbuf[idx] = tanhf(Fbuf[idx]) * sigmoid(acc)   (C unused; no G buffer)
// ---------------------------------------------------------------------------
template<int GATE>
__global__ __launch_bounds__(256)
void gemm_conv(const float* __restrict__ A, const float* __restrict__ W,
               float* __restrict__ C, float* __restrict__ Fbuf,
               int M, int N, int K)
{
    __shared__ float As[32][68];
    __shared__ float Bs[32][68];
    const int tid = threadIdx.x;
    const int m0 = blockIdx.y * 64;
    const int n0 = blockIdx.x * 64;
    const int tm = tid >> 4;
    const int tn = tid & 15;
    const int lr = tid >> 3;          // 0..31
    const int lk = (tid & 7) << 2;    // 0,4,...,28

    float acc[4][4] = {};

    #pragma unroll
    for (int tap = 0; tap < 2; ++tap) {
        const float* Wt = W + (size_t)tap * K * N;
        for (int k0 = 0; k0 < K; k0 += 32) {
            // A tile (shifted for tap 0)
            #pragma unroll
            for (int p = 0; p < 2; ++p) {
                const int mm = lr + p * 32;
                const int mrow = m0 + mm;
                float4 v;
                if (tap == 0) {
                    const int t = mrow & (T_SEQ - 1);
                    if (t == 0) v = make_float4(0.f, 0.f, 0.f, 0.f);
                    else v = *reinterpret_cast<const float4*>(
                        &A[(size_t)(mrow - 1) * K + k0 + lk]);
                } else {
                    v = *reinterpret_cast<const float4*>(
                        &A[(size_t)mrow * K + k0 + lk]);
                }
                As[lk + 0][mm] = v.x; As[lk + 1][mm] = v.y;
                As[lk + 2][mm] = v.z; As[lk + 3][mm] = v.w;
            }
            // B tile: row-major [K,N] direct: Bs[kk][nn] = Wt[(k0+kk)*N + n0+nn]
            #pragma unroll
            for (int p = 0; p < 2; ++p) {
                const int kk = (tid >> 4) + p * 16;
                const int nn = (tid & 15) << 2;
                const float4 v = *reinterpret_cast<const float4*>(
                    &Wt[(size_t)(k0 + kk) * N + n0 + nn]);
                *reinterpret_cast<float4*>(&Bs[kk][nn]) = v;
            }
            __syncthreads();
            #pragma unroll
            for (int kk = 0; kk < 32; ++kk) {
                float a[4], b[4];
                #pragma unroll
                for (int i = 0; i < 4; ++i) a[i] = As[kk][tm * 4 + i];
                #pragma unroll
                for (int j = 0; j < 4; ++j) b[j] = Bs[kk][tn * 4 + j];
                #pragma unroll
                for (int i = 0; i < 4; ++i)
                    #pragma unroll
                    for (int j = 0; j < 4; ++j)
                        acc[i][j] = fmaf(a[i], b[j], acc[i][j]);
            }
            __syncthreads();
        }
    }

    #pragma unroll
    for (int i = 0; i < 4; ++i) {
        const size_t row = (size_t)(m0 + tm * 4 + i);
        #pragma unroll
        for (int j = 0; j < 4; ++j) {
            const size_t idx = row * N + (n0 + tn * 4 + j);
            if (GATE == 0) {
                C[idx] = acc[i][j];
            } else {
                const float g = 1.0f / (1.0f + expf(-acc[i][j]));
                Fbuf[idx] = tanhf(Fbuf[idx]) * g;
            }
        }
    }
}

// ---------------------------------------------------------------------------
// Per-(b,c) sequential scan over T:
//   scale = cummax(|cv|); kv = cumprod(cv/scale)  (complex, in-place over k)
//   y = x * scale
// 8192 threads; consecutive c -> coalesced float2 accesses each t.
// ---------------------------------------------------------------------------
__global__ __launch_bounds__(256)
void scan_kernel(float* __restrict__ kre, const float* __restrict__ x,
                 float* __restrict__ y)
{
    const int tid = blockIdx.x * blockDim.x + threadIdx.x;   // 0..8191
    const int b = tid >> 10;        // / C_DIM
    const int c = tid & (C_DIM - 1);
    float m = 0.0f, pr = 1.0f, pi = 0.0f;
    size_t idx2 = (size_t)b * T_SEQ * (2 * C_DIM) + 2 * c;
    size_t idx1 = (size_t)b * T_SEQ * C_DIM + c;
    for (int t = 0; t < T_SEQ; ++t) {
        const float2 v = *reinterpret_cast<const float2*>(&kre[idx2]);
        const float a = sqrtf(v.x * v.x + v.y * v.y);
        m = fmaxf(m, a);
        const float inv = 1.0f / m;
        const float r0 = v.x * inv, r1 = v.y * inv;
        const float nr = pr * r0 - pi * r1;
        const float ni = pr * r1 + pi * r0;
        pr = nr; pi = ni;
        *reinterpret_cast<float2*>(&kre[idx2]) = make_float2(pr, pi);
        y[idx1] = x[idx1] * m;
        idx2 += 2 * C_DIM;
        idx1 += C_DIM;
    }
}

// ---------------------------------------------------------------------------
// Launch: GEMM1 -> scan -> GEMM2 -> conv_f -> conv_g(+gate) -> GEMM_o(*=)
// ws layout: [ k/re : 16384*2048 f32 (reused as F,G region after GEMM2) ]
//            [ y    : 16384*1024 f32 ]   total ~201 MB
// ---------------------------------------------------------------------------
extern "C" void kernel_launch(void* const* d_in, const int* in_sizes, int n_in,
                              void* d_out, int out_size, void* d_ws, size_t ws_size,
                              hipStream_t stream)
{
    const float* x  = (const float*)d_in[0];
    const float* Wk = (const float*)d_in[1];
    const float* Wa = (const float*)d_in[2];
    const float* Wf = (const float*)d_in[3];
    const float* Wg = (const float*)d_in[4];
    const float* Wo = (const float*)d_in[5];
    float* out = (float*)d_out;

    const int M = 8 * T_SEQ;                 // 16384 rows
    float* kre = (float*)d_ws;               // [M, 2C]
    float* y   = kre + (size_t)M * 2 * C_DIM;// [M, C]
    float* F   = kre;                        // reuse after GEMM2

    // 1) k = x @ Wk^T   (Wk: [2C, C])
    gemm_bt<0><<<dim3(2 * C_DIM / 64, M / 64), 256, 0, stream>>>(
        x, Wk, kre, M, 2 * C_DIM, C_DIM);

    // 2) scan: kv (in-place), y = x * scale
    scan_kernel<<<(8 * C_DIM) / 256, 256, 0, stream>>>(kre, x, y);

    // 3) act = re @ Wa^T  -> d_out   (Wa: [C, 2C])
    gemm_bt<0><<<dim3(C_DIM / 64, M / 64), 256, 0, stream>>>(
        kre, Wa, out, M, C_DIM, 2 * C_DIM);

    // 4) F = causal_conv(y, Wf)
    gemm_conv<0><<<dim3(C_DIM / 64, M / 64), 256, 0, stream>>>(
        y, Wf, F, nullptr, M, C_DIM, C_DIM);

    // 5) h = tanh(F) * sigmoid(causal_conv(y, Wg))  -> F (in place)
    gemm_conv<1><<<dim3(C_DIM / 64, M / 64), 256, 0, stream>>>(
        y, Wg, nullptr, F, M, C_DIM, C_DIM);

    // 6) out = act * (h @ Wo^T)   (Wo: [C, C]; EPI=1 multiplies into d_out)
    gemm_bt<1><<<dim3(C_DIM / 64, M / 64), 256, 0, stream>>>(
        F, Wo, out, M, C_DIM, C_DIM);
}

// Round 2
// 1211.132 us; speedup vs baseline: 4.2720x; 4.2720x over previous
//
#include <hip/hip_runtime.h>
#include <cmath>

#define T_SEQ 2048
#define C_DIM 1024
#define BM 128
#define BN 128
#define BK 32

typedef unsigned short u16;
typedef unsigned int u32;
typedef short bf16x8 __attribute__((ext_vector_type(8)));
typedef float f32x4 __attribute__((ext_vector_type(4)));
typedef unsigned short u16x8 __attribute__((ext_vector_type(8)));

#define AS1 __attribute__((address_space(1)))
#define AS3 __attribute__((address_space(3)))

__device__ __forceinline__ u16 f2bf(float f) {
    u32 u = __builtin_bit_cast(u32, f);
    u32 r = u + 0x7fffu + ((u >> 16) & 1u);
    return (u16)(r >> 16);
}
__device__ __forceinline__ float bf2f(u16 h) {
    return __builtin_bit_cast(float, (u32)h << 16);
}
__device__ __forceinline__ void gl_lds16(const void* g, void* l) {
    __builtin_amdgcn_global_load_lds((const AS1 u32*)g, (AS3 u32*)l, 16, 0, 0);
}

// ---------------------------------------------------------------------------
// MFMA GEMM: C[M,N] (f32) = A[M,K] @ B^T with B[N,K] bf16 row-major (K-contig).
// ASTAGE: 0 = A is bf16, staged via global_load_lds (supports per-pass t-1 shift)
//         1 = A is f32, reg-staged with on-the-fly bf16 convert
//         2 = A is f32, reg-staged SPLIT (hi+lo) + B0lo: acc += Ah*Bh+Al*Bh+Ah*Bl
// EPI:    0 = C = acc    1 = C *= acc
// SHIFTMASK: bit p set -> pass p reads A row (m-1), zeros at t==0 (causal conv)
// Tiles 128x128, BK=32, 256 thr (4 waves 2x2), 16x16x32 bf16 MFMA, dbuf LDS,
// XOR slot swizzle (slot' = slot ^ ((row>>1)&3)) for ~conflict-free ds_read_b128.
// ---------------------------------------------------------------------------
template<int ASTAGE, int NPASS, int EPI, int SHIFTMASK>
__global__ __launch_bounds__(256)
void mfma_gemm(const void* __restrict__ Abase, const u16* __restrict__ B0,
               const u16* __restrict__ B1, const u16* __restrict__ B0lo,
               float* __restrict__ C, int M, int N, int K)
{
    constexpr int TILES = (ASTAGE == 2) ? 4 : 2;   // tiles per buffer
    __shared__ u16 lds[TILES * 2 * 4096];          // 2 buffers, 8KB per tile
    const int tid  = threadIdx.x;
    const int lane = tid & 63;
    const int wid  = tid >> 6;
    const int wr = wid >> 1, wc = wid & 1;
    const int m0 = blockIdx.y * BM;
    const int n0 = blockIdx.x * BN;
    const int KIT = K / BK;
    const int NT  = NPASS * KIT;

    f32x4 acc[4][4] = {};

    auto stage = [&](int it, int buf) {
        const int p  = it / KIT;
        const int k0 = (it - p * KIT) * BK;
        u16* base = &lds[buf * TILES * 4096];
        // ---- B tile (always bf16 via global_load_lds) ----
        const u16* Bp = (p == 0) ? B0 : B1;
        #pragma unroll
        for (int i = 0; i < 2; ++i) {
            const int chunk = wid + 4 * i;
            const int rloc  = chunk * 16 + (lane >> 2);
            const int slot  = (lane & 3) ^ ((rloc >> 1) & 3);
            gl_lds16(Bp + (size_t)(n0 + rloc) * K + k0 + slot * 8,
                     base + 4096 + chunk * 512);
        }
        if constexpr (ASTAGE == 2) {
            #pragma unroll
            for (int i = 0; i < 2; ++i) {
                const int chunk = wid + 4 * i;
                const int rloc  = chunk * 16 + (lane >> 2);
                const int slot  = (lane & 3) ^ ((rloc >> 1) & 3);
                gl_lds16(B0lo + (size_t)(n0 + rloc) * K + k0 + slot * 8,
                         base + 12288 + chunk * 512);
            }
        }
        // ---- A tile ----
        if constexpr (ASTAGE == 0) {
            const u16* Ap = (const u16*)Abase;
            const int sh = (SHIFTMASK >> p) & 1;
            #pragma unroll
            for (int i = 0; i < 2; ++i) {
                const int chunk = wid + 4 * i;
                const int rloc  = chunk * 16 + (lane >> 2);
                int grow = m0 + rloc - sh;
                if (grow < 0) grow = 0;
                const int slot = (lane & 3) ^ ((rloc >> 1) & 3);
                gl_lds16(Ap + (size_t)grow * K + k0 + slot * 8,
                         base + chunk * 512);
            }
        } else {
            const float* Af = (const float*)Abase;
            const int r = tid >> 1, h = tid & 1;
            const float* src = Af + (size_t)(m0 + r) * K + k0 + h * 16;
            const float4 q0 = ((const float4*)src)[0];
            const float4 q1 = ((const float4*)src)[1];
            const float4 q2 = ((const float4*)src)[2];
            const float4 q3 = ((const float4*)src)[3];
            float v[16] = {q0.x,q0.y,q0.z,q0.w, q1.x,q1.y,q1.z,q1.w,
                           q2.x,q2.y,q2.z,q2.w, q3.x,q3.y,q3.z,q3.w};
            u16 hi[16];
            #pragma unroll
            for (int j = 0; j < 16; ++j) hi[j] = f2bf(v[j]);
            const int rb = r * 32;
            #pragma unroll
            for (int s2 = 0; s2 < 2; ++s2) {
                const int slot = 2 * h + s2;
                const int sp = slot ^ ((r >> 1) & 3);
                u16x8 w;
                #pragma unroll
                for (int j = 0; j < 8; ++j) w[j] = hi[s2 * 8 + j];
                *(u16x8*)&base[rb + sp * 8] = w;
            }
            if constexpr (ASTAGE == 2) {
                u16 lo[16];
                #pragma unroll
                for (int j = 0; j < 16; ++j) lo[j] = f2bf(v[j] - bf2f(hi[j]));
                #pragma unroll
                for (int s2 = 0; s2 < 2; ++s2) {
                    const int slot = 2 * h + s2;
                    const int sp = slot ^ ((r >> 1) & 3);
                    u16x8 w;
                    #pragma unroll
                    for (int j = 0; j < 8; ++j) w[j] = lo[s2 * 8 + j];
                    *(u16x8*)&base[8192 + rb + sp * 8] = w;
                }
            }
        }
    };

    auto compute = [&](int buf) {
        const u16* base = &lds[buf * TILES * 4096];
        bf16x8 a[4], b[4];
        #pragma unroll
        for (int f = 0; f < 4; ++f) {
            const int row = wr * 64 + f * 16 + (lane & 15);
            const int sp  = ((lane >> 4) & 3) ^ ((row >> 1) & 3);
            a[f] = *(const bf16x8*)&base[row * 32 + sp * 8];
            const int rowb = wc * 64 + f * 16 + (lane & 15);
            const int spb  = ((lane >> 4) & 3) ^ ((rowb >> 1) & 3);
            b[f] = *(const bf16x8*)&base[4096 + rowb * 32 + spb * 8];
        }
        if constexpr (ASTAGE == 2) {
            bf16x8 al[4], bl[4];
            #pragma unroll
            for (int f = 0; f < 4; ++f) {
                const int row = wr * 64 + f * 16 + (lane & 15);
                const int sp  = ((lane >> 4) & 3) ^ ((row >> 1) & 3);
                al[f] = *(const bf16x8*)&base[8192 + row * 32 + sp * 8];
                const int rowb = wc * 64 + f * 16 + (lane & 15);
                const int spb  = ((lane >> 4) & 3) ^ ((rowb >> 1) & 3);
                bl[f] = *(const bf16x8*)&base[12288 + rowb * 32 + spb * 8];
            }
            #pragma unroll
            for (int fm = 0; fm < 4; ++fm)
                #pragma unroll
                for (int fn = 0; fn < 4; ++fn) {
                    acc[fm][fn] = __builtin_amdgcn_mfma_f32_16x16x32_bf16(a[fm],  b[fn],  acc[fm][fn], 0, 0, 0);
                    acc[fm][fn] = __builtin_amdgcn_mfma_f32_16x16x32_bf16(al[fm], b[fn],  acc[fm][fn], 0, 0, 0);
                    acc[fm][fn] = __builtin_amdgcn_mfma_f32_16x16x32_bf16(a[fm],  bl[fn], acc[fm][fn], 0, 0, 0);
                }
        } else {
            #pragma unroll
            for (int fm = 0; fm < 4; ++fm)
                #pragma unroll
                for (int fn = 0; fn < 4; ++fn)
                    acc[fm][fn] = __builtin_amdgcn_mfma_f32_16x16x32_bf16(a[fm], b[fn], acc[fm][fn], 0, 0, 0);
        }
    };

    stage(0, 0);
    int cur = 0;
    for (int it = 0; it < NT; ++it) {
        __syncthreads();   // staged data for buf[cur] landed; prior reads of buf[cur^1] done
        if constexpr (ASTAGE == 0 && SHIFTMASK != 0) {
            const int p = it / KIT;
            if (((SHIFTMASK >> p) & 1) && (m0 % T_SEQ == 0)) {
                if (tid < 4) {
                    u16x8 z = {0,0,0,0,0,0,0,0};
                    *(u16x8*)&lds[cur * TILES * 4096 + tid * 8] = z;  // zero t==0 row
                }
                __syncthreads();
            }
        }
        if (it + 1 < NT) stage(it + 1, cur ^ 1);
        compute(cur);
        cur ^= 1;
    }

    // ---- epilogue: C/D layout col=lane&15, row=(lane>>4)*4+r ----
    const int crow0 = m0 + wr * 64 + ((lane >> 4) << 2);
    const int ccol  = n0 + wc * 64 + (lane & 15);
    #pragma unroll
    for (int fm = 0; fm < 4; ++fm)
        #pragma unroll
        for (int fn = 0; fn < 4; ++fn)
            #pragma unroll
            for (int r = 0; r < 4; ++r) {
                const size_t idx = (size_t)(crow0 + fm * 16 + r) * N + ccol + fn * 16;
                if (EPI == 0) C[idx] = acc[fm][fn][r];
                else          C[idx] = C[idx] * acc[fm][fn][r];
            }
}

// ---------------------------------------------------------------------------
// Per-(b,c) sequential scan: kv = cumprod(cv/cummax|cv|) in-place (f32),
// yb = bf16(x * scale).
// ---------------------------------------------------------------------------
__global__ __launch_bounds__(256)
void scan_kernel(float* __restrict__ kre, const float* __restrict__ x,
                 u16* __restrict__ yb)
{
    const int tid = blockIdx.x * blockDim.x + threadIdx.x;   // 0..8191
    const int b = tid >> 10;
    const int c = tid & (C_DIM - 1);
    float m = 0.0f, pr = 1.0f, pi = 0.0f;
    size_t idx2 = (size_t)b * T_SEQ * (2 * C_DIM) + 2 * c;
    size_t idx1 = (size_t)b * T_SEQ * C_DIM + c;
    for (int t = 0; t < T_SEQ; ++t) {
        const float2 v = *reinterpret_cast<const float2*>(&kre[idx2]);
        const float a = sqrtf(v.x * v.x + v.y * v.y);
        m = fmaxf(m, a);
        const float inv = 1.0f / m;
        const float r0 = v.x * inv, r1 = v.y * inv;
        const float nr = pr * r0 - pi * r1;
        const float ni = pr * r1 + pi * r0;
        pr = nr; pi = ni;
        *reinterpret_cast<float2*>(&kre[idx2]) = make_float2(pr, pi);
        yb[idx1] = f2bf(x[idx1] * m);
        idx2 += 2 * C_DIM;
        idx1 += C_DIM;
    }
}

// ---------------------------------------------------------------------------
// Prep kernels
// ---------------------------------------------------------------------------
__global__ void cvt_bf16(const float* __restrict__ src, u16* __restrict__ dst, int n)
{
    const int i = (blockIdx.x * blockDim.x + threadIdx.x) * 4;
    if (i >= n) return;
    const float4 v = *(const float4*)&src[i];
    ushort4 o;
    o.x = f2bf(v.x); o.y = f2bf(v.y); o.z = f2bf(v.z); o.w = f2bf(v.w);
    *(ushort4*)&dst[i] = o;
}

__global__ void cvt_split(const float* __restrict__ src, u16* __restrict__ hi,
                          u16* __restrict__ lo, int n)
{
    const int i = (blockIdx.x * blockDim.x + threadIdx.x) * 4;
    if (i >= n) return;
    const float4 v = *(const float4*)&src[i];
    ushort4 h, l;
    h.x = f2bf(v.x); h.y = f2bf(v.y); h.z = f2bf(v.z); h.w = f2bf(v.w);
    l.x = f2bf(v.x - bf2f(h.x)); l.y = f2bf(v.y - bf2f(h.y));
    l.z = f2bf(v.z - bf2f(h.z)); l.w = f2bf(v.w - bf2f(h.w));
    *(ushort4*)&hi[i] = h;
    *(ushort4*)&lo[i] = l;
}

// Wf/Wg [2,K=1024,N=1024] (tap,k,n) -> Wfgt [2,2048,1024] bf16 (tap, n(F then G), k)
__global__ __launch_bounds__(256)
void wtrans(const float* __restrict__ Wf, const float* __restrict__ Wg,
            u16* __restrict__ dst)
{
    __shared__ float tile[64][65];
    const int z = blockIdx.z;                       // 0,1 = Wf taps; 2,3 = Wg taps
    const float* src = ((z < 2) ? Wf : Wg) + (size_t)(z & 1) * C_DIM * C_DIM;
    u16* d = dst + (size_t)(z & 1) * (2 * C_DIM) * C_DIM
                 + ((z < 2) ? (size_t)0 : (size_t)C_DIM * C_DIM);
    const int k0 = blockIdx.x * 64;
    const int n0 = blockIdx.y * 64;
    const int tx = threadIdx.x & 63, ty = threadIdx.x >> 6;
    #pragma unroll
    for (int i = 0; i < 16; ++i) {
        const int r = ty + i * 4;
        tile[r][tx] = src[(size_t)(k0 + r) * C_DIM + n0 + tx];
    }
    __syncthreads();
    #pragma unroll
    for (int i = 0; i < 16; ++i) {
        const int r = ty + i * 4;
        d[(size_t)(n0 + r) * C_DIM + k0 + tx] = f2bf(tile[tx][r]);
    }
}

// h = tanh(F) * sigmoid(G): FG [M,2048] f32 (F cols 0..1023, G cols 1024..2047)
__global__ void gate_kernel(const float* __restrict__ FG, u16* __restrict__ hb, int total)
{
    const int i = (blockIdx.x * blockDim.x + threadIdx.x) * 4;
    if (i >= total) return;
    const int m = i >> 10;
    const int c = i & (C_DIM - 1);
    const float4 f = *(const float4*)&FG[(size_t)m * 2048 + c];
    const float4 g = *(const float4*)&FG[(size_t)m * 2048 + 1024 + c];
    ushort4 o;
    o.x = f2bf(tanhf(f.x) * (1.0f / (1.0f + expf(-g.x))));
    o.y = f2bf(tanhf(f.y) * (1.0f / (1.0f + expf(-g.y))));
    o.z = f2bf(tanhf(f.z) * (1.0f / (1.0f + expf(-g.z))));
    o.w = f2bf(tanhf(f.w) * (1.0f / (1.0f + expf(-g.w))));
    *(ushort4*)&hb[i] = o;
}

// ---------------------------------------------------------------------------
// ws layout (bytes):
//   0         : kre f32 [16384,2048] 134.2MB  (reused as FG f32 after scan+GEMM2)
//   134217728 : yb  u16 [16384,1024]  33.6MB  (reused as hb after conv)
//   167772160 : Wkhi u16 [2048,1024] 4.2MB
//   171966464 : Wklo u16 4.2MB
//   176160768 : Wab  u16 [1024,2048] 4.2MB
//   180355072 : Wfgt u16 [2,2048,1024] 8.4MB
//   188743680 : Wob  u16 [1024,1024] 2.1MB     total ~191MB
// ---------------------------------------------------------------------------
extern "C" void kernel_launch(void* const* d_in, const int* in_sizes, int n_in,
                              void* d_out, int out_size, void* d_ws, size_t ws_size,
                              hipStream_t stream)
{
    const float* x  = (const float*)d_in[0];
    const float* Wk = (const float*)d_in[1];
    const float* Wa = (const float*)d_in[2];
    const float* Wf = (const float*)d_in[3];
    const float* Wg = (const float*)d_in[4];
    const float* Wo = (const float*)d_in[5];
    float* out = (float*)d_out;

    const int M = 8 * T_SEQ;                 // 16384
    float* kre = (float*)d_ws;
    u16* yb   = (u16*)((char*)d_ws + 134217728ull);
    u16* Wkhi = (u16*)((char*)d_ws + 167772160ull);
    u16* Wklo = Wkhi + 2048 * 1024;
    u16* Wab  = Wklo + 2048 * 1024;
    u16* Wfgt = Wab  + 2048 * 1024;
    u16* Wob  = Wfgt + 2ull * 2048 * 1024;

    // --- weight prep ---
    cvt_split<<<(2048 * 1024 / 4 + 255) / 256, 256, 0, stream>>>(Wk, Wkhi, Wklo, 2048 * 1024);
    cvt_bf16 <<<(2048 * 1024 / 4 + 255) / 256, 256, 0, stream>>>(Wa, Wab, 2048 * 1024);
    cvt_bf16 <<<(1024 * 1024 / 4 + 255) / 256, 256, 0, stream>>>(Wo, Wob, 1024 * 1024);
    wtrans   <<<dim3(16, 16, 4), 256, 0, stream>>>(Wf, Wg, Wfgt);

    // 1) kre = x @ Wk^T  (split-compensated bf16 MFMA)
    mfma_gemm<2, 1, 0, 0><<<dim3(2048 / BN, M / BM), 256, 0, stream>>>(
        x, Wkhi, nullptr, Wklo, kre, M, 2048, 1024);

    // 2) scan (in-place kv f32), yb = bf16(x*scale)
    scan_kernel<<<8192 / 256, 256, 0, stream>>>(kre, x, yb);

    // 3) out = kv @ Wa^T  (A reg-staged f32->bf16)
    mfma_gemm<1, 1, 0, 0><<<dim3(1024 / BN, M / BM), 256, 0, stream>>>(
        kre, Wab, nullptr, nullptr, out, M, 1024, 2048);

    // 4) FG = [shift(yb); yb] @ Wfgt_taps  -> f32 over kre region
    mfma_gemm<0, 2, 0, 1><<<dim3(2048 / BN, M / BM), 256, 0, stream>>>(
        yb, Wfgt, Wfgt + 2048 * 1024, nullptr, kre, M, 2048, 1024);

    // 5) hb = bf16(tanh(F)*sigmoid(G))  (over yb region)
    gate_kernel<<<(M * 1024 / 4) / 256, 256, 0, stream>>>(kre, yb, M * 1024);

    // 6) out *= hb @ Wo^T
    mfma_gemm<0, 1, 1, 0><<<dim3(1024 / BN, M / BM), 256, 0, stream>>>(
        yb, Wob, nullptr, nullptr, out, M, 1024, 1024);
}

// Round 3
// 817.335 us; speedup vs baseline: 6.3303x; 1.4818x over previous
//
#include <hip/hip_runtime.h>
#include <cmath>

#define T_SEQ 2048
#define C_DIM 1024
#define BM 128
#define BN 128
#define BK 32

typedef unsigned short u16;
typedef unsigned int u32;
typedef short bf16x8 __attribute__((ext_vector_type(8)));
typedef float f32x4 __attribute__((ext_vector_type(4)));
typedef unsigned short u16x8 __attribute__((ext_vector_type(8)));

#define AS1 __attribute__((address_space(1)))
#define AS3 __attribute__((address_space(3)))

__device__ __forceinline__ u16 f2bf(float f) {
    u32 u = __builtin_bit_cast(u32, f);
    u32 r = u + 0x7fffu + ((u >> 16) & 1u);
    return (u16)(r >> 16);
}
__device__ __forceinline__ float bf2f(u16 h) {
    return __builtin_bit_cast(float, (u32)h << 16);
}
__device__ __forceinline__ void gl_lds16(const void* g, void* l) {
    __builtin_amdgcn_global_load_lds((const AS1 u32*)g, (AS3 u32*)l, 16, 0, 0);
}

// ---------------------------------------------------------------------------
// MFMA GEMM: C[M,N] (f32) = A[M,K] @ B^T with B[N,K] bf16 row-major (K-contig).
// ASTAGE: 0 = A is bf16, staged via global_load_lds (supports per-pass t-1 shift)
//         1 = A is f32, reg-staged with on-the-fly bf16 convert
//         2 = A is f32, reg-staged SPLIT (hi+lo) + B0lo: acc += Ah*Bh+Al*Bh+Ah*Bl
// EPI:    0 = C = acc    1 = C *= acc
// SHIFTMASK: bit p set -> pass p reads A row (m-1), zeros at t==0 (causal conv)
// ---------------------------------------------------------------------------
template<int ASTAGE, int NPASS, int EPI, int SHIFTMASK>
__global__ __launch_bounds__(256)
void mfma_gemm(const void* __restrict__ Abase, const u16* __restrict__ B0,
               const u16* __restrict__ B1, const u16* __restrict__ B0lo,
               float* __restrict__ C, int M, int N, int K)
{
    constexpr int TILES = (ASTAGE == 2) ? 4 : 2;   // tiles per buffer
    __shared__ u16 lds[TILES * 2 * 4096];          // 2 buffers, 8KB per tile
    const int tid  = threadIdx.x;
    const int lane = tid & 63;
    const int wid  = tid >> 6;
    const int wr = wid >> 1, wc = wid & 1;
    const int m0 = blockIdx.y * BM;
    const int n0 = blockIdx.x * BN;
    const int KIT = K / BK;
    const int NT  = NPASS * KIT;

    f32x4 acc[4][4] = {};

    auto stage = [&](int it, int buf) {
        const int p  = it / KIT;
        const int k0 = (it - p * KIT) * BK;
        u16* base = &lds[buf * TILES * 4096];
        // ---- B tile ----
        const u16* Bp = (p == 0) ? B0 : B1;
        #pragma unroll
        for (int i = 0; i < 2; ++i) {
            const int chunk = wid + 4 * i;
            const int rloc  = chunk * 16 + (lane >> 2);
            const int slot  = (lane & 3) ^ ((rloc >> 1) & 3);
            gl_lds16(Bp + (size_t)(n0 + rloc) * K + k0 + slot * 8,
                     base + 4096 + chunk * 512);
        }
        if constexpr (ASTAGE == 2) {
            #pragma unroll
            for (int i = 0; i < 2; ++i) {
                const int chunk = wid + 4 * i;
                const int rloc  = chunk * 16 + (lane >> 2);
                const int slot  = (lane & 3) ^ ((rloc >> 1) & 3);
                gl_lds16(B0lo + (size_t)(n0 + rloc) * K + k0 + slot * 8,
                         base + 12288 + chunk * 512);
            }
        }
        // ---- A tile ----
        if constexpr (ASTAGE == 0) {
            const u16* Ap = (const u16*)Abase;
            const int sh = (SHIFTMASK >> p) & 1;
            #pragma unroll
            for (int i = 0; i < 2; ++i) {
                const int chunk = wid + 4 * i;
                const int rloc  = chunk * 16 + (lane >> 2);
                int grow = m0 + rloc - sh;
                if (grow < 0) grow = 0;
                const int slot = (lane & 3) ^ ((rloc >> 1) & 3);
                gl_lds16(Ap + (size_t)grow * K + k0 + slot * 8,
                         base + chunk * 512);
            }
        } else {
            const float* Af = (const float*)Abase;
            const int r = tid >> 1, h = tid & 1;
            const float* src = Af + (size_t)(m0 + r) * K + k0 + h * 16;
            const float4 q0 = ((const float4*)src)[0];
            const float4 q1 = ((const float4*)src)[1];
            const float4 q2 = ((const float4*)src)[2];
            const float4 q3 = ((const float4*)src)[3];
            float v[16] = {q0.x,q0.y,q0.z,q0.w, q1.x,q1.y,q1.z,q1.w,
                           q2.x,q2.y,q2.z,q2.w, q3.x,q3.y,q3.z,q3.w};
            u16 hi[16];
            #pragma unroll
            for (int j = 0; j < 16; ++j) hi[j] = f2bf(v[j]);
            const int rb = r * 32;
            #pragma unroll
            for (int s2 = 0; s2 < 2; ++s2) {
                const int slot = 2 * h + s2;
                const int sp = slot ^ ((r >> 1) & 3);
                u16x8 w;
                #pragma unroll
                for (int j = 0; j < 8; ++j) w[j] = hi[s2 * 8 + j];
                *(u16x8*)&base[rb + sp * 8] = w;
            }
            if constexpr (ASTAGE == 2) {
                u16 lo[16];
                #pragma unroll
                for (int j = 0; j < 16; ++j) lo[j] = f2bf(v[j] - bf2f(hi[j]));
                #pragma unroll
                for (int s2 = 0; s2 < 2; ++s2) {
                    const int slot = 2 * h + s2;
                    const int sp = slot ^ ((r >> 1) & 3);
                    u16x8 w;
                    #pragma unroll
                    for (int j = 0; j < 8; ++j) w[j] = lo[s2 * 8 + j];
                    *(u16x8*)&base[8192 + rb + sp * 8] = w;
                }
            }
        }
    };

    auto compute = [&](int buf) {
        const u16* base = &lds[buf * TILES * 4096];
        bf16x8 a[4], b[4];
        #pragma unroll
        for (int f = 0; f < 4; ++f) {
            const int row = wr * 64 + f * 16 + (lane & 15);
            const int sp  = ((lane >> 4) & 3) ^ ((row >> 1) & 3);
            a[f] = *(const bf16x8*)&base[row * 32 + sp * 8];
            const int rowb = wc * 64 + f * 16 + (lane & 15);
            const int spb  = ((lane >> 4) & 3) ^ ((rowb >> 1) & 3);
            b[f] = *(const bf16x8*)&base[4096 + rowb * 32 + spb * 8];
        }
        if constexpr (ASTAGE == 2) {
            bf16x8 al[4], bl[4];
            #pragma unroll
            for (int f = 0; f < 4; ++f) {
                const int row = wr * 64 + f * 16 + (lane & 15);
                const int sp  = ((lane >> 4) & 3) ^ ((row >> 1) & 3);
                al[f] = *(const bf16x8*)&base[8192 + row * 32 + sp * 8];
                const int rowb = wc * 64 + f * 16 + (lane & 15);
                const int spb  = ((lane >> 4) & 3) ^ ((rowb >> 1) & 3);
                bl[f] = *(const bf16x8*)&base[12288 + rowb * 32 + spb * 8];
            }
            #pragma unroll
            for (int fm = 0; fm < 4; ++fm)
                #pragma unroll
                for (int fn = 0; fn < 4; ++fn) {
                    acc[fm][fn] = __builtin_amdgcn_mfma_f32_16x16x32_bf16(a[fm],  b[fn],  acc[fm][fn], 0, 0, 0);
                    acc[fm][fn] = __builtin_amdgcn_mfma_f32_16x16x32_bf16(al[fm], b[fn],  acc[fm][fn], 0, 0, 0);
                    acc[fm][fn] = __builtin_amdgcn_mfma_f32_16x16x32_bf16(a[fm],  bl[fn], acc[fm][fn], 0, 0, 0);
                }
        } else {
            #pragma unroll
            for (int fm = 0; fm < 4; ++fm)
                #pragma unroll
                for (int fn = 0; fn < 4; ++fn)
                    acc[fm][fn] = __builtin_amdgcn_mfma_f32_16x16x32_bf16(a[fm], b[fn], acc[fm][fn], 0, 0, 0);
        }
    };

    stage(0, 0);
    int cur = 0;
    for (int it = 0; it < NT; ++it) {
        __syncthreads();
        if constexpr (ASTAGE == 0 && SHIFTMASK != 0) {
            const int p = it / KIT;
            if (((SHIFTMASK >> p) & 1) && (m0 % T_SEQ == 0)) {
                if (tid < 4) {
                    u16x8 z = {0,0,0,0,0,0,0,0};
                    *(u16x8*)&lds[cur * TILES * 4096 + tid * 8] = z;
                }
                __syncthreads();
            }
        }
        if (it + 1 < NT) stage(it + 1, cur ^ 1);
        compute(cur);
        cur ^= 1;
    }

    const int crow0 = m0 + wr * 64 + ((lane >> 4) << 2);
    const int ccol  = n0 + wc * 64 + (lane & 15);
    #pragma unroll
    for (int fm = 0; fm < 4; ++fm)
        #pragma unroll
        for (int fn = 0; fn < 4; ++fn)
            #pragma unroll
            for (int r = 0; r < 4; ++r) {
                const size_t idx = (size_t)(crow0 + fm * 16 + r) * N + ccol + fn * 16;
                if (EPI == 0) C[idx] = acc[fm][fn][r];
                else          C[idx] = C[idx] * acc[fm][fn][r];
            }
}

// ---------------------------------------------------------------------------
// Segmented parallel scan over T (3-phase):
//   P1: per-segment max of |cv|  -> LDS Hillis-Steele max-scan (32 segments)
//   P2: per-segment complex product of cv/m (m seeded by exclusive prefix max);
//       emits yb = bf16(x*m)     -> LDS complex-product scan
//   P3: re-read, recompute, seed with exclusive prefix product, write kv.
// Workgroup: 16 channels x 32 segments (512 thr); grid 8*64=512 blocks.
// ---------------------------------------------------------------------------
#define SSEG 32
#define SCHB 16
#define SSL (T_SEQ / SSEG)   // 64

__global__ __launch_bounds__(512)
void scan_kernel(float* __restrict__ kre, const float* __restrict__ x,
                 u16* __restrict__ yb)
{
    __shared__ float  lmax[SSEG][SCHB];
    __shared__ float2 lprod[SSEG][SCHB];
    const int blk = blockIdx.x;
    const int b   = blk >> 6;
    const int c0  = (blk & 63) * SCHB;
    const int ch  = threadIdx.x & (SCHB - 1);
    const int seg = threadIdx.x >> 4;            // 0..31
    const int c   = c0 + ch;
    const int t0  = seg * SSL;
    const size_t stride2 = 2 * C_DIM;
    const size_t base2 = (size_t)b * T_SEQ * stride2 + 2 * c + (size_t)t0 * stride2;
    const size_t base1 = (size_t)b * T_SEQ * C_DIM + c + (size_t)t0 * C_DIM;

    // P1: segment max
    float m = 0.f;
    {
        size_t idx = base2;
        for (int t = 0; t < SSL; ++t) {
            const float2 v = *(const float2*)&kre[idx];
            m = fmaxf(m, sqrtf(v.x * v.x + v.y * v.y));
            idx += stride2;
        }
    }
    lmax[seg][ch] = m;
    __syncthreads();
    #pragma unroll
    for (int s = 1; s < SSEG; s <<= 1) {
        const float v = lmax[seg][ch];
        const float u = (seg >= s) ? lmax[seg - s][ch] : 0.f;
        __syncthreads();
        lmax[seg][ch] = fmaxf(v, u);
        __syncthreads();
    }
    const float premax = (seg > 0) ? lmax[seg - 1][ch] : 0.f;

    // P2: segment complex product with correct running max; emit yb
    float pr = 1.f, pi = 0.f;
    {
        m = premax;
        size_t idx = base2, idx1 = base1;
        for (int t = 0; t < SSL; ++t) {
            const float2 v = *(const float2*)&kre[idx];
            const float a = sqrtf(v.x * v.x + v.y * v.y);
            m = fmaxf(m, a);
            const float inv = 1.f / m;
            const float r0 = v.x * inv, r1 = v.y * inv;
            const float nr = pr * r0 - pi * r1;
            const float ni = pr * r1 + pi * r0;
            pr = nr; pi = ni;
            yb[idx1] = f2bf(x[idx1] * m);
            idx += stride2; idx1 += C_DIM;
        }
    }
    lprod[seg][ch] = make_float2(pr, pi);
    __syncthreads();
    #pragma unroll
    for (int s = 1; s < SSEG; s <<= 1) {
        const float2 v = lprod[seg][ch];
        const float2 u = (seg >= s) ? lprod[seg - s][ch] : make_float2(1.f, 0.f);
        __syncthreads();
        lprod[seg][ch] = make_float2(u.x * v.x - u.y * v.y,
                                     u.x * v.y + u.y * v.x);
        __syncthreads();
    }
    if (seg > 0) { const float2 pp = lprod[seg - 1][ch]; pr = pp.x; pi = pp.y; }
    else         { pr = 1.f; pi = 0.f; }

    // P3: recompute and write kv
    m = premax;
    size_t idx = base2;
    for (int t = 0; t < SSL; ++t) {
        const float2 v = *(const float2*)&kre[idx];
        const float a = sqrtf(v.x * v.x + v.y * v.y);
        m = fmaxf(m, a);
        const float inv = 1.f / m;
        const float r0 = v.x * inv, r1 = v.y * inv;
        const float nr = pr * r0 - pi * r1;
        const float ni = pr * r1 + pi * r0;
        pr = nr; pi = ni;
        *(float2*)&kre[idx] = make_float2(pr, pi);
        idx += stride2;
    }
}

// ---------------------------------------------------------------------------
// Prep kernels
// ---------------------------------------------------------------------------
__global__ void cvt_bf16(const float* __restrict__ src, u16* __restrict__ dst, int n)
{
    const int i = (blockIdx.x * blockDim.x + threadIdx.x) * 4;
    if (i >= n) return;
    const float4 v = *(const float4*)&src[i];
    ushort4 o;
    o.x = f2bf(v.x); o.y = f2bf(v.y); o.z = f2bf(v.z); o.w = f2bf(v.w);
    *(ushort4*)&dst[i] = o;
}

__global__ void cvt_split(const float* __restrict__ src, u16* __restrict__ hi,
                          u16* __restrict__ lo, int n)
{
    const int i = (blockIdx.x * blockDim.x + threadIdx.x) * 4;
    if (i >= n) return;
    const float4 v = *(const float4*)&src[i];
    ushort4 h, l;
    h.x = f2bf(v.x); h.y = f2bf(v.y); h.z = f2bf(v.z); h.w = f2bf(v.w);
    l.x = f2bf(v.x - bf2f(h.x)); l.y = f2bf(v.y - bf2f(h.y));
    l.z = f2bf(v.z - bf2f(h.z)); l.w = f2bf(v.w - bf2f(h.w));
    *(ushort4*)&hi[i] = h;
    *(ushort4*)&lo[i] = l;
}

// Wf/Wg [2,K,N] (tap,k,n) -> Wfgt [2,2048,1024] bf16 (tap, n(F then G), k)
__global__ __launch_bounds__(256)
void wtrans(const float* __restrict__ Wf, const float* __restrict__ Wg,
            u16* __restrict__ dst)
{
    __shared__ float tile[64][65];
    const int z = blockIdx.z;
    const float* src = ((z < 2) ? Wf : Wg) + (size_t)(z & 1) * C_DIM * C_DIM;
    u16* d = dst + (size_t)(z & 1) * (2 * C_DIM) * C_DIM
                 + ((z < 2) ? (size_t)0 : (size_t)C_DIM * C_DIM);
    const int k0 = blockIdx.x * 64;
    const int n0 = blockIdx.y * 64;
    const int tx = threadIdx.x & 63, ty = threadIdx.x >> 6;
    #pragma unroll
    for (int i = 0; i < 16; ++i) {
        const int r = ty + i * 4;
        tile[r][tx] = src[(size_t)(k0 + r) * C_DIM + n0 + tx];
    }
    __syncthreads();
    #pragma unroll
    for (int i = 0; i < 16; ++i) {
        const int r = ty + i * 4;
        d[(size_t)(n0 + r) * C_DIM + k0 + tx] = f2bf(tile[tx][r]);
    }
}

// h = tanh(F) * sigmoid(G)
__global__ void gate_kernel(const float* __restrict__ FG, u16* __restrict__ hb, int total)
{
    const int i = (blockIdx.x * blockDim.x + threadIdx.x) * 4;
    if (i >= total) return;
    const int m = i >> 10;
    const int c = i & (C_DIM - 1);
    const float4 f = *(const float4*)&FG[(size_t)m * 2048 + c];
    const float4 g = *(const float4*)&FG[(size_t)m * 2048 + 1024 + c];
    ushort4 o;
    o.x = f2bf(tanhf(f.x) * (1.0f / (1.0f + expf(-g.x))));
    o.y = f2bf(tanhf(f.y) * (1.0f / (1.0f + expf(-g.y))));
    o.z = f2bf(tanhf(f.z) * (1.0f / (1.0f + expf(-g.z))));
    o.w = f2bf(tanhf(f.w) * (1.0f / (1.0f + expf(-g.w))));
    *(ushort4*)&hb[i] = o;
}

// ---------------------------------------------------------------------------
// ws layout unchanged (~191MB)
// ---------------------------------------------------------------------------
extern "C" void kernel_launch(void* const* d_in, const int* in_sizes, int n_in,
                              void* d_out, int out_size, void* d_ws, size_t ws_size,
                              hipStream_t stream)
{
    const float* x  = (const float*)d_in[0];
    const float* Wk = (const float*)d_in[1];
    const float* Wa = (const float*)d_in[2];
    const float* Wf = (const float*)d_in[3];
    const float* Wg = (const float*)d_in[4];
    const float* Wo = (const float*)d_in[5];
    float* out = (float*)d_out;

    const int M = 8 * T_SEQ;
    float* kre = (float*)d_ws;
    u16* yb   = (u16*)((char*)d_ws + 134217728ull);
    u16* Wkhi = (u16*)((char*)d_ws + 167772160ull);
    u16* Wklo = Wkhi + 2048 * 1024;
    u16* Wab  = Wklo + 2048 * 1024;
    u16* Wfgt = Wab  + 2048 * 1024;
    u16* Wob  = Wfgt + 2ull * 2048 * 1024;

    cvt_split<<<(2048 * 1024 / 4 + 255) / 256, 256, 0, stream>>>(Wk, Wkhi, Wklo, 2048 * 1024);
    cvt_bf16 <<<(2048 * 1024 / 4 + 255) / 256, 256, 0, stream>>>(Wa, Wab, 2048 * 1024);
    cvt_bf16 <<<(1024 * 1024 / 4 + 255) / 256, 256, 0, stream>>>(Wo, Wob, 1024 * 1024);
    wtrans   <<<dim3(16, 16, 4), 256, 0, stream>>>(Wf, Wg, Wfgt);

    // 1) kre = x @ Wk^T  (split-compensated bf16 MFMA)
    mfma_gemm<2, 1, 0, 0><<<dim3(2048 / BN, M / BM), 256, 0, stream>>>(
        x, Wkhi, nullptr, Wklo, kre, M, 2048, 1024);

    // 2) segmented parallel scan
    scan_kernel<<<512, 512, 0, stream>>>(kre, x, yb);

    // 3) out = kv @ Wa^T
    mfma_gemm<1, 1, 0, 0><<<dim3(1024 / BN, M / BM), 256, 0, stream>>>(
        kre, Wab, nullptr, nullptr, out, M, 1024, 2048);

    // 4) FG = [shift(yb); yb] @ Wfgt_taps
    mfma_gemm<0, 2, 0, 1><<<dim3(2048 / BN, M / BM), 256, 0, stream>>>(
        yb, Wfgt, Wfgt + 2048 * 1024, nullptr, kre, M, 2048, 1024);

    // 5) hb = bf16(tanh(F)*sigmoid(G))
    gate_kernel<<<(M * 1024 / 4) / 256, 256, 0, stream>>>(kre, yb, M * 1024);

    // 6) out *= hb @ Wo^T
    mfma_gemm<0, 1, 1, 0><<<dim3(1024 / BN, M / BM), 256, 0, stream>>>(
        yb, Wob, nullptr, nullptr, out, M, 1024, 1024);
}